// Round 3
// baseline (196.262 us; speedup 1.0000x reference)
//
#include <hip/hip_runtime.h>
#include <math.h>

#define FEAT 4096
#define BATCH 4096
#define ROWS_PER_BLOCK 4

// Kernel 1: each block computes ROWS_PER_BLOCK rows.
// Round-0/1 lesson: loop-body structure (register ILP, async-LDS MLP) does NOT
// move the 70.6 µs — duration is invariant => bottleneck is per-workgroup fixed
// cost (4096 tiny WGs, 2 barriers + full vmcnt drain each, no cross-block load
// overlap). This version amortizes: 4 rows/block, ONE barrier per block, no
// fences between rows so row r+1 loads may overlap row r compute.
//
// Bit-exactness: per-row op order is IDENTICAL to the absmax=0.0 kernel:
// per-thread strided fmaf chain -> 64-lane butterfly -> wave-order 0..3 sum
// -> sqrt -> fmax. Rows are independent, so absmax must remain 0.0.
__global__ __launch_bounds__(256) void row_dist_kernel(
    const float* __restrict__ o1, const float* __restrict__ o2,
    const float* __restrict__ o3, float* __restrict__ row_out)
{
    const int tid = threadIdx.x;
    const int wave = tid >> 6;
    const int lane = tid & 63;
    const int row0 = blockIdx.x * ROWS_PER_BLOCK;

    __shared__ float ls13[ROWS_PER_BLOCK][4];
    __shared__ float ls12[ROWS_PER_BLOCK][4];

    #pragma unroll
    for (int r = 0; r < ROWS_PER_BLOCK; ++r) {
        const int row = row0 + r;
        const float4* p1 = (const float4*)(o1 + (size_t)row * FEAT);
        const float4* p2 = (const float4*)(o2 + (size_t)row * FEAT);
        const float4* p3 = (const float4*)(o3 + (size_t)row * FEAT);

        float s13 = 0.0f, s12 = 0.0f;
        #pragma unroll
        for (int k = 0; k < 4; ++k) {
            const int idx = tid + k * 256;
            const float4 a = p1[idx];
            const float4 b = p2[idx];
            const float4 c = p3[idx];
            float d;
            d = a.x - c.x; s13 = fmaf(d, d, s13);
            d = a.y - c.y; s13 = fmaf(d, d, s13);
            d = a.z - c.z; s13 = fmaf(d, d, s13);
            d = a.w - c.w; s13 = fmaf(d, d, s13);
            d = a.x - b.x; s12 = fmaf(d, d, s12);
            d = a.y - b.y; s12 = fmaf(d, d, s12);
            d = a.z - b.z; s12 = fmaf(d, d, s12);
            d = a.w - b.w; s12 = fmaf(d, d, s12);
        }

        // wave(64)-level butterfly reduce — no barrier needed
        #pragma unroll
        for (int off = 32; off > 0; off >>= 1) {
            s13 += __shfl_down(s13, off, 64);
            s12 += __shfl_down(s12, off, 64);
        }
        if (lane == 0) { ls13[r][wave] = s13; ls12[r][wave] = s12; }
    }

    __syncthreads();   // single barrier for the whole block

    if (tid < ROWS_PER_BLOCK) {
        // same wave-order 0,1,2,3 summation as the absmax=0.0 kernel
        const float t13 = ls13[tid][0] + ls13[tid][1] + ls13[tid][2] + ls13[tid][3];
        const float t12 = ls12[tid][0] + ls12[tid][1] + ls12[tid][2] + ls12[tid][3];
        const float compare = 2.0f - sqrtf(t13) + sqrtf(t12);
        row_out[row0 + tid] = fmaxf(compare, 0.0f);
    }
}

// Kernel 2: reduce the BATCH row values, scale by BATCH (broadcast-sum semantics).
// UNCHANGED: current summation order gives absmax == 0.0 vs the JAX reference.
__global__ __launch_bounds__(1024) void final_reduce_kernel(
    const float* __restrict__ row_vals, float* __restrict__ out)
{
    const int tid = threadIdx.x;
    float s = 0.0f;
    #pragma unroll
    for (int k = 0; k < BATCH / 1024; ++k) s += row_vals[tid + k * 1024];

    #pragma unroll
    for (int off = 32; off > 0; off >>= 1) s += __shfl_down(s, off, 64);

    __shared__ float ls[16];
    const int wave = tid >> 6;
    const int lane = tid & 63;
    if (lane == 0) ls[wave] = s;
    __syncthreads();
    if (tid == 0) {
        float t = 0.0f;
        #pragma unroll
        for (int i = 0; i < 16; ++i) t += ls[i];
        out[0] = t * (float)BATCH;
    }
}

extern "C" void kernel_launch(void* const* d_in, const int* in_sizes, int n_in,
                              void* d_out, int out_size, void* d_ws, size_t ws_size,
                              hipStream_t stream) {
    const float* o1 = (const float*)d_in[0];
    const float* o2 = (const float*)d_in[1];
    const float* o3 = (const float*)d_in[2];
    float* row_ws = (float*)d_ws;          // BATCH floats of scratch
    float* out = (float*)d_out;            // single fp32 scalar

    row_dist_kernel<<<BATCH / ROWS_PER_BLOCK, 256, 0, stream>>>(o1, o2, o3, row_ws);
    final_reduce_kernel<<<1, 1024, 0, stream>>>(row_ws, out);
}

// Round 4
// 191.069 us; speedup vs baseline: 1.0272x; 1.0272x over previous
//
#include <hip/hip_runtime.h>
#include <math.h>

#define FEAT 4096
#define BATCH 4096

// Kernel 1: one block per row (round-0 shape — best measured: 20 waves/CU).
// Change vs round 0: all 12 float4 loads issued, then sched_barrier(0) pins
// them BEFORE any use — the compiler cannot re-serialize to VGPR=28 (its
// round-0 behavior), so 12 loads/wave (~12 KiB) stay in flight. Combined with
// ~20 waves/CU this triples per-CU outstanding bytes vs all prior rounds
// (R0: 20w x 3KiB, R1: 6w x 12KiB drained, R2: 16w x 3KiB -> all ~2.8 TB/s).
//
// Bit-exactness: identical per-row op order to the absmax=0.0 kernel
// (per-thread k=0..3 fmaf chain, 64-lane butterfly, wave-order 0..3 sum,
// sqrt, fmax).
__global__ __launch_bounds__(256) void row_dist_kernel(
    const float* __restrict__ o1, const float* __restrict__ o2,
    const float* __restrict__ o3, float* __restrict__ row_out)
{
    const int row = blockIdx.x;
    const int tid = threadIdx.x;
    const float4* p1 = (const float4*)(o1 + (size_t)row * FEAT) + tid;
    const float4* p2 = (const float4*)(o2 + (size_t)row * FEAT) + tid;
    const float4* p3 = (const float4*)(o3 + (size_t)row * FEAT) + tid;

    // Issue all 12 loads (a,b,c interleaved so compute can start at vmcnt(9)).
    const float4 a0 = p1[0];   const float4 b0 = p2[0];   const float4 c0 = p3[0];
    const float4 a1 = p1[256]; const float4 b1 = p2[256]; const float4 c1 = p3[256];
    const float4 a2 = p1[512]; const float4 b2 = p2[512]; const float4 c2 = p3[512];
    const float4 a3 = p1[768]; const float4 b3 = p2[768]; const float4 c3 = p3[768];

    // Hard scheduling fence: nothing crosses. Forces all 12 float4 live
    // (VGPR ~64) -> 12 outstanding loads per wave, compiler cannot undo.
    __builtin_amdgcn_sched_barrier(0);

    float s13 = 0.0f, s12 = 0.0f;
    float d;
    d = a0.x - c0.x; s13 = fmaf(d, d, s13);
    d = a0.y - c0.y; s13 = fmaf(d, d, s13);
    d = a0.z - c0.z; s13 = fmaf(d, d, s13);
    d = a0.w - c0.w; s13 = fmaf(d, d, s13);
    d = a0.x - b0.x; s12 = fmaf(d, d, s12);
    d = a0.y - b0.y; s12 = fmaf(d, d, s12);
    d = a0.z - b0.z; s12 = fmaf(d, d, s12);
    d = a0.w - b0.w; s12 = fmaf(d, d, s12);

    d = a1.x - c1.x; s13 = fmaf(d, d, s13);
    d = a1.y - c1.y; s13 = fmaf(d, d, s13);
    d = a1.z - c1.z; s13 = fmaf(d, d, s13);
    d = a1.w - c1.w; s13 = fmaf(d, d, s13);
    d = a1.x - b1.x; s12 = fmaf(d, d, s12);
    d = a1.y - b1.y; s12 = fmaf(d, d, s12);
    d = a1.z - b1.z; s12 = fmaf(d, d, s12);
    d = a1.w - b1.w; s12 = fmaf(d, d, s12);

    d = a2.x - c2.x; s13 = fmaf(d, d, s13);
    d = a2.y - c2.y; s13 = fmaf(d, d, s13);
    d = a2.z - c2.z; s13 = fmaf(d, d, s13);
    d = a2.w - c2.w; s13 = fmaf(d, d, s13);
    d = a2.x - b2.x; s12 = fmaf(d, d, s12);
    d = a2.y - b2.y; s12 = fmaf(d, d, s12);
    d = a2.z - b2.z; s12 = fmaf(d, d, s12);
    d = a2.w - b2.w; s12 = fmaf(d, d, s12);

    d = a3.x - c3.x; s13 = fmaf(d, d, s13);
    d = a3.y - c3.y; s13 = fmaf(d, d, s13);
    d = a3.z - c3.z; s13 = fmaf(d, d, s13);
    d = a3.w - c3.w; s13 = fmaf(d, d, s13);
    d = a3.x - b3.x; s12 = fmaf(d, d, s12);
    d = a3.y - b3.y; s12 = fmaf(d, d, s12);
    d = a3.z - b3.z; s12 = fmaf(d, d, s12);
    d = a3.w - b3.w; s12 = fmaf(d, d, s12);

    // wave(64)-level butterfly reduce
    #pragma unroll
    for (int off = 32; off > 0; off >>= 1) {
        s13 += __shfl_down(s13, off, 64);
        s12 += __shfl_down(s12, off, 64);
    }

    __shared__ float ls13[4];
    __shared__ float ls12[4];
    const int wave = tid >> 6;
    const int lane = tid & 63;
    if (lane == 0) { ls13[wave] = s13; ls12[wave] = s12; }
    __syncthreads();
    if (tid == 0) {
        const float t13 = ls13[0] + ls13[1] + ls13[2] + ls13[3];
        const float t12 = ls12[0] + ls12[1] + ls12[2] + ls12[3];
        const float compare = 2.0f - sqrtf(t13) + sqrtf(t12);
        row_out[row] = fmaxf(compare, 0.0f);
    }
}

// Kernel 2: reduce the BATCH row values, scale by BATCH (broadcast-sum semantics).
// UNCHANGED: current summation order gives absmax == 0.0 vs the JAX reference.
__global__ __launch_bounds__(1024) void final_reduce_kernel(
    const float* __restrict__ row_vals, float* __restrict__ out)
{
    const int tid = threadIdx.x;
    float s = 0.0f;
    #pragma unroll
    for (int k = 0; k < BATCH / 1024; ++k) s += row_vals[tid + k * 1024];

    #pragma unroll
    for (int off = 32; off > 0; off >>= 1) s += __shfl_down(s, off, 64);

    __shared__ float ls[16];
    const int wave = tid >> 6;
    const int lane = tid & 63;
    if (lane == 0) ls[wave] = s;
    __syncthreads();
    if (tid == 0) {
        float t = 0.0f;
        #pragma unroll
        for (int i = 0; i < 16; ++i) t += ls[i];
        out[0] = t * (float)BATCH;
    }
}

extern "C" void kernel_launch(void* const* d_in, const int* in_sizes, int n_in,
                              void* d_out, int out_size, void* d_ws, size_t ws_size,
                              hipStream_t stream) {
    const float* o1 = (const float*)d_in[0];
    const float* o2 = (const float*)d_in[1];
    const float* o3 = (const float*)d_in[2];
    float* row_ws = (float*)d_ws;          // BATCH floats of scratch
    float* out = (float*)d_out;            // single fp32 scalar

    row_dist_kernel<<<BATCH, 256, 0, stream>>>(o1, o2, o3, row_ws);
    final_reduce_kernel<<<1, 1024, 0, stream>>>(row_ws, out);
}

// Round 6
// 173.846 us; speedup vs baseline: 1.1289x; 1.0991x over previous
//
#include <hip/hip_runtime.h>
#include <math.h>

#define FEAT 4096
#define BATCH 4096

// Native vector type: __builtin_nontemporal_load requires int/float/ptr or a
// VECTOR of such — HIP_vector_type<float,4> (a struct) is rejected (round 4).
typedef float nt_float4 __attribute__((ext_vector_type(4)));

// Kernel 1: one block per row (round-0 shape — best measured: 20 waves/CU).
//
// Rounds 0-3 established: dur is invariant (70.6 µs) under register ILP,
// async-LDS MLP, rows/block, and sched fences. Counters show hbm_bytes is
// EXACTLY half of the 201.6 MB read and total BW is EXACTLY 2x HBM BW every
// round => the L3-miss stream gates (pseudo-random ~50% line residue left by
// the harness's restore thrashing the 256 MiB L3; scattered 128B misses cap
// HBM at ~1.43 TB/s row-miss rate), L3 hits ride hidden.
//
// This round: nontemporal loads on the 3 input streams. If nt bypasses /
// no-allocates the Infinity Cache on reads, all 201.6 MB arrives as
// SEQUENTIAL HBM streams (~6.3 TB/s => ~32 µs). Tripwire: FETCH_SIZE should
// double to ~201 MB. If FETCH_SIZE is unchanged, nt is retention-only on
// gfx950 and the kernel is at the scattered-miss roofline.
//
// Bit-exactness: nt loads return identical bits; per-row op order identical
// to the absmax=0.0 kernel.
__global__ __launch_bounds__(256) void row_dist_kernel(
    const float* __restrict__ o1, const float* __restrict__ o2,
    const float* __restrict__ o3, float* __restrict__ row_out)
{
    const int row = blockIdx.x;
    const int tid = threadIdx.x;
    const nt_float4* p1 = (const nt_float4*)(o1 + (size_t)row * FEAT);
    const nt_float4* p2 = (const nt_float4*)(o2 + (size_t)row * FEAT);
    const nt_float4* p3 = (const nt_float4*)(o3 + (size_t)row * FEAT);

    float s13 = 0.0f, s12 = 0.0f;
    #pragma unroll
    for (int k = 0; k < 4; ++k) {
        const int idx = tid + k * 256;
        const nt_float4 a = __builtin_nontemporal_load(&p1[idx]);
        const nt_float4 b = __builtin_nontemporal_load(&p2[idx]);
        const nt_float4 c = __builtin_nontemporal_load(&p3[idx]);
        float d;
        d = a.x - c.x; s13 = fmaf(d, d, s13);
        d = a.y - c.y; s13 = fmaf(d, d, s13);
        d = a.z - c.z; s13 = fmaf(d, d, s13);
        d = a.w - c.w; s13 = fmaf(d, d, s13);
        d = a.x - b.x; s12 = fmaf(d, d, s12);
        d = a.y - b.y; s12 = fmaf(d, d, s12);
        d = a.z - b.z; s12 = fmaf(d, d, s12);
        d = a.w - b.w; s12 = fmaf(d, d, s12);
    }

    // wave(64)-level butterfly reduce
    #pragma unroll
    for (int off = 32; off > 0; off >>= 1) {
        s13 += __shfl_down(s13, off, 64);
        s12 += __shfl_down(s12, off, 64);
    }

    __shared__ float ls13[4];
    __shared__ float ls12[4];
    const int wave = tid >> 6;
    const int lane = tid & 63;
    if (lane == 0) { ls13[wave] = s13; ls12[wave] = s12; }
    __syncthreads();
    if (tid == 0) {
        const float t13 = ls13[0] + ls13[1] + ls13[2] + ls13[3];
        const float t12 = ls12[0] + ls12[1] + ls12[2] + ls12[3];
        const float compare = 2.0f - sqrtf(t13) + sqrtf(t12);
        row_out[row] = fmaxf(compare, 0.0f);
    }
}

// Kernel 2: reduce the BATCH row values, scale by BATCH (broadcast-sum semantics).
// UNCHANGED: current summation order gives absmax == 0.0 vs the JAX reference.
__global__ __launch_bounds__(1024) void final_reduce_kernel(
    const float* __restrict__ row_vals, float* __restrict__ out)
{
    const int tid = threadIdx.x;
    float s = 0.0f;
    #pragma unroll
    for (int k = 0; k < BATCH / 1024; ++k) s += row_vals[tid + k * 1024];

    #pragma unroll
    for (int off = 32; off > 0; off >>= 1) s += __shfl_down(s, off, 64);

    __shared__ float ls[16];
    const int wave = tid >> 6;
    const int lane = tid & 63;
    if (lane == 0) ls[wave] = s;
    __syncthreads();
    if (tid == 0) {
        float t = 0.0f;
        #pragma unroll
        for (int i = 0; i < 16; ++i) t += ls[i];
        out[0] = t * (float)BATCH;
    }
}

extern "C" void kernel_launch(void* const* d_in, const int* in_sizes, int n_in,
                              void* d_out, int out_size, void* d_ws, size_t ws_size,
                              hipStream_t stream) {
    const float* o1 = (const float*)d_in[0];
    const float* o2 = (const float*)d_in[1];
    const float* o3 = (const float*)d_in[2];
    float* row_ws = (float*)d_ws;          // BATCH floats of scratch
    float* out = (float*)d_out;            // single fp32 scalar

    row_dist_kernel<<<BATCH, 256, 0, stream>>>(o1, o2, o3, row_ws);
    final_reduce_kernel<<<1, 1024, 0, stream>>>(row_ws, out);
}